// Round 14
// baseline (286.365 us; speedup 1.0000x reference)
//
#include <hip/hip_runtime.h>
#include <hip/hip_bf16.h>
#include <cstdint>
#include <cstddef>

typedef __attribute__((ext_vector_type(8))) short bf16x8;
typedef __attribute__((ext_vector_type(4))) float f32x4;

static constexpr int CB  = 2;
static constexpr int CS  = 2048;
static constexpr int CH  = 2048;
static constexpr int CNH = 32;
static constexpr int CNKV = 8;
static constexpr int CHD = 64;
static constexpr int CTHD = 3072; // (NH + 2*NKV)*HD

__device__ __forceinline__ void gload_lds16(const void* g, void* l) {
  __builtin_amdgcn_global_load_lds(
      (const __attribute__((address_space(1))) unsigned int*)g,
      (__attribute__((address_space(3))) unsigned int*)l, 16, 0, 0);
}

__device__ __forceinline__ unsigned short bfbits(float f) {
  __hip_bfloat16 h = __float2bfloat16(f);
  return *(unsigned short*)&h;
}

// ---------------- elementwise fp32 -> bf16 ----------------
__global__ void conv_bf16(const float* __restrict__ in, __hip_bfloat16* __restrict__ out, int n) {
  const int i = (blockIdx.x * 256 + threadIdx.x) * 4;
  if (i >= n) return;
  const float4 v = *(const float4*)(in + i);
  out[i]     = __float2bfloat16(v.x);
  out[i + 1] = __float2bfloat16(v.y);
  out[i + 2] = __float2bfloat16(v.z);
  out[i + 3] = __float2bfloat16(v.w);
}

// ---------------- tiled transpose + convert (fp32 RxC -> bf16 CxR) ----------------
__global__ __launch_bounds__(256) void transpose_conv(const float* __restrict__ in,
                                                      __hip_bfloat16* __restrict__ out,
                                                      int R, int Cc) {
  __shared__ float t[32][33];
  const int nbx = Cc >> 5;
  const int bx = blockIdx.x % nbx, by = blockIdx.x / nbx;
  const int c0 = bx << 5, r0 = by << 5;
  const int tx = threadIdx.x & 31, ty = threadIdx.x >> 5; // ty 0..7
#pragma unroll
  for (int j = 0; j < 32; j += 8)
    t[ty + j][tx] = in[(size_t)(r0 + ty + j) * Cc + c0 + tx];
  __syncthreads();
#pragma unroll
  for (int j = 0; j < 32; j += 8)
    out[(size_t)(c0 + ty + j) * R + r0 + tx] = __float2bfloat16(t[tx][ty + j]);
}

// ---------------- phased GEMM: 128x256 tile, BK=64, counted vmcnt (T3/T4/T5) ----------------
template <typename OutT>
__global__ __launch_bounds__(512) void gemm_ph(const __hip_bfloat16* __restrict__ A,
                                               const __hip_bfloat16* __restrict__ Bt,
                                               OutT* __restrict__ C, int M, int N, int K) {
  __shared__ __hip_bfloat16 As[2][128 * 64];
  __shared__ __hip_bfloat16 Bs[2][256 * 64];
  const int tid = threadIdx.x;
  const int lane = tid & 63;
  const int wave = tid >> 6;             // 0..7
  const int nTn = N >> 8;
  const int nwg = gridDim.x;
  const int wg = (blockIdx.x & 7) * (nwg >> 3) + (blockIdx.x >> 3);
  const int tm = wg / nTn, tn = wg % nTn;
  const size_t m0 = (size_t)tm * 128, n0 = (size_t)tn * 256;
  const __hip_bfloat16* Ag = A + m0 * K;
  const __hip_bfloat16* Bg = Bt + n0 * K;
  const int wr = wave >> 2, wc = wave & 3;
  const int rsel = lane & 15, hi = lane >> 4;

  f32x4 acc[4][4];
#pragma unroll
  for (int mf = 0; mf < 4; ++mf)
#pragma unroll
    for (int nf = 0; nf < 4; ++nf) acc[mf][nf] = (f32x4){0.f, 0.f, 0.f, 0.f};

  auto stageA = [&](int u) {
    const int k0 = u << 6, buf = u & 1;
#pragma unroll
    for (int i = 0; i < 2; ++i) {
      const int c = i * 512 + tid;       // chunk 0..1023
      const int r = c >> 3;
      const int swz = ((c & 7) ^ (r & 7)) << 3;
      gload_lds16(Ag + (size_t)r * K + k0 + swz, &As[buf][(i * 512 + wave * 64) * 8]);
    }
  };
  auto stageB = [&](int u) {
    const int k0 = u << 6, buf = u & 1;
#pragma unroll
    for (int i = 0; i < 4; ++i) {
      const int c = i * 512 + tid;       // chunk 0..2047
      const int r = c >> 3;
      const int swz = ((c & 7) ^ (r & 7)) << 3;
      gload_lds16(Bg + (size_t)r * K + k0 + swz, &Bs[buf][(i * 512 + wave * 64) * 8]);
    }
  };

  bf16x8 af[4][2];
  auto readA = [&](int buf) {
#pragma unroll
    for (int mf = 0; mf < 4; ++mf) {
      const int row = wr * 64 + mf * 16 + rsel;
      const int r7 = row & 7;
      af[mf][0] = *(const bf16x8*)&As[buf][row * 64 + ((hi ^ r7) << 3)];
      af[mf][1] = *(const bf16x8*)&As[buf][row * 64 + (((4 | hi) ^ r7) << 3)];
    }
  };
  auto mm = [&](int buf, int nfb) {
    bf16x8 bfr[2][2];
#pragma unroll
    for (int nf = 0; nf < 2; ++nf) {
      const int row = wc * 64 + (nfb + nf) * 16 + rsel;
      const int r7 = row & 7;
      bfr[nf][0] = *(const bf16x8*)&Bs[buf][row * 64 + ((hi ^ r7) << 3)];
      bfr[nf][1] = *(const bf16x8*)&Bs[buf][row * 64 + (((4 | hi) ^ r7) << 3)];
    }
    __builtin_amdgcn_s_setprio(1);
#pragma unroll
    for (int mf = 0; mf < 4; ++mf)
#pragma unroll
      for (int nf = 0; nf < 2; ++nf)
#pragma unroll
        for (int kk = 0; kk < 2; ++kk)
          acc[mf][nfb + nf] =
              __builtin_amdgcn_mfma_f32_16x16x32_bf16(af[mf][kk], bfr[nf][kk], acc[mf][nfb + nf], 0, 0, 0);
    __builtin_amdgcn_s_setprio(0);
  };

  const int T = K >> 7;                  // iterations (2 K-tiles each); K=2048 -> 8
  const int UMAX = 2 * T;
  stageA(0); stageB(0); stageA(1); stageB(1);

  for (int t = 0; t < T; ++t) {
    const int u0 = 2 * t, u1 = 2 * t + 1;
    // ---- phase 1 ----
    asm volatile("s_waitcnt vmcnt(2)" ::: "memory");
    __builtin_amdgcn_sched_barrier(0);
    __builtin_amdgcn_s_barrier();
    __builtin_amdgcn_sched_barrier(0);
    if (t >= 1) stageB(u1);
    readA(0);
    mm(0, 0);
    // ---- phase 2 ----
    __builtin_amdgcn_sched_barrier(0);
    __builtin_amdgcn_s_barrier();
    __builtin_amdgcn_sched_barrier(0);
    if (u0 + 2 < UMAX) stageA(u0 + 2);
    mm(0, 2);
    // ---- phase 3 ----
    if (t == T - 1) {
      asm volatile("s_waitcnt vmcnt(0)" ::: "memory");
    } else {
      asm volatile("s_waitcnt vmcnt(2)" ::: "memory");
    }
    __builtin_amdgcn_sched_barrier(0);
    __builtin_amdgcn_s_barrier();
    __builtin_amdgcn_sched_barrier(0);
    if (u0 + 2 < UMAX) stageB(u0 + 2);
    readA(1);
    mm(1, 0);
    // ---- phase 4 ----
    __builtin_amdgcn_sched_barrier(0);
    __builtin_amdgcn_s_barrier();
    __builtin_amdgcn_sched_barrier(0);
    if (u1 + 2 < UMAX) stageA(u1 + 2);
    mm(1, 2);
  }

  const int rowb = hi << 2;
#pragma unroll
  for (int mf = 0; mf < 4; ++mf)
#pragma unroll
    for (int nf = 0; nf < 4; ++nf) {
      const size_t r0 = m0 + wr * 64 + mf * 16 + rowb;
      const size_t cc = n0 + wc * 64 + nf * 16 + rsel;
#pragma unroll
      for (int j = 0; j < 4; ++j) {
        const float v = acc[mf][nf][j];
        if constexpr (sizeof(OutT) == 4)
          C[(r0 + j) * N + cc] = v;
        else
          C[(r0 + j) * N + cc] = __float2bfloat16(v);
      }
    }
}

// ---------------- RoPE + extract Q/K (Q pre-scaled by 0.125*log2e) ----------------
__global__ void rope_extract(const __hip_bfloat16* __restrict__ qkv,
                             __hip_bfloat16* __restrict__ Q,
                             __hip_bfloat16* __restrict__ Kr) {
  const int idx = blockIdx.x * 256 + threadIdx.x;
  const int i = idx & 31;
  const int hs = (idx >> 5) % 40;     // 0..31 = Q heads, 32..39 = K heads
  const int r = idx / (40 * 32);      // b*S + s
  const int srow = r & (CS - 1);
  const int b = r >> 11;
  const float inv = exp2f(-(float)i * (13.287712379549449f / 32.0f)); // 10000^(-i/32)
  const float ang = (float)srow * inv;
  const float sn = sinf(ang), cs = cosf(ang);
  const int col = (hs < CNH) ? hs * CHD + 2 * i : CH + (hs - CNH) * CHD + 2 * i;
  const float t1 = __bfloat162float(qkv[(size_t)r * CTHD + col]);
  const float t2 = __bfloat162float(qkv[(size_t)r * CTHD + col + 1]);
  // Q heads carry the whole softmax input scale: 1/sqrt(64) * log2(e)
  const float scl = (hs < CNH) ? 0.18033688011112042f : 1.0f;
  const float ev = (t1 * cs - t2 * sn) * scl;
  const float ov = (t1 * sn + t2 * cs) * scl;
  __hip_bfloat16* dst;
  if (hs < CNH)
    dst = Q + ((((size_t)b * CNH + hs) * CS + srow) * CHD + 2 * i);
  else
    dst = Kr + ((((size_t)b * CNKV + (hs - CNH)) * CS + srow) * CHD + 2 * i);
  dst[0] = __float2bfloat16(ev);
  dst[1] = __float2bfloat16(ov);
}

// ---------------- V extract + transpose: VT[b][kvh][d][s] ----------------
__global__ __launch_bounds__(256) void v_transpose(const __hip_bfloat16* __restrict__ qkv,
                                                   __hip_bfloat16* __restrict__ VT) {
  __shared__ __hip_bfloat16 t[64][72];
  const int bi = blockIdx.x;
  const int stile = bi & 31;
  const int kvh = (bi >> 5) & 7;
  const int b = bi >> 8;
  const int tx = threadIdx.x & 63;
  const int ty = threadIdx.x >> 6; // 0..3
  const int s0 = stile * 64;
#pragma unroll
  for (int j = 0; j < 16; ++j) {
    const int sl = ty * 16 + j;
    t[sl][tx] = qkv[(size_t)(b * CS + s0 + sl) * CTHD + (CH + CNKV * CHD) + kvh * CHD + tx];
  }
  __syncthreads();
#pragma unroll
  for (int j = 0; j < 16; ++j) {
    const int dl = ty * 16 + j;
    VT[(((size_t)b * CNKV + kvh) * CHD + dl) * CS + s0 + tx] = t[tx][dl];
  }
}

// ---------------- GQA causal flash attention ----------------
// Block = (b, kvh, headpair, qw32): 2 waves = 2 q-heads; each wave owns 32 q-rows
// as TWO independent 16-row sub-tiles (R9 body) against shared LDS K/V.
// Grid stays 2048 (packing density), LDS 33792 -> 4 blocks/CU; kc/vf LDS reads
// amortize 2x per wave. K dbuf, V single-buffer with mid-iteration barrier (R12
// sync ring). Swapped-operand MFMA, log2-domain scores, defer-max, padded P-LDS.
__global__ __launch_bounds__(128) void attn_fa(const __hip_bfloat16* __restrict__ Q,
                                               const __hip_bfloat16* __restrict__ Kr,
                                               const __hip_bfloat16* __restrict__ VT,
                                               const int* __restrict__ mask,
                                               __hip_bfloat16* __restrict__ O) {
  __shared__ __hip_bfloat16 Ks[2][64 * 64];
  __shared__ __hip_bfloat16 Vs[64 * 64];
  __shared__ __hip_bfloat16 P4[2][2][16][72];   // [wave][subtile]
  const int kvh = blockIdx.x & 7;          // xcd owns one kv-head
  const int slot = blockIdx.x >> 3;        // 0..255
  const int qw = 63 - (slot >> 2);         // heavy-first, 32-row q tiles
  const int b = (slot >> 1) & 1;
  const int hp = slot & 1;
  const int tid = threadIdx.x;             // 0..127
  const int wave = tid >> 6, lane = tid & 63;
  const int h = kvh * 4 + hp * 2 + wave;   // this wave's q-head
  const int q0 = qw * 32;
  const int rsel = lane & 15;              // this lane's q-row within sub-tile
  const int hi = lane >> 4;                // 0..3
  const int k8 = hi * 8;
  const int rowb = hi * 4;
  const __hip_bfloat16* Qp = Q + (((size_t)b * CNH + h) * CS + q0) * CHD;
  const __hip_bfloat16* Kp = Kr + ((size_t)b * CNKV + kvh) * CS * CHD;
  const __hip_bfloat16* Vp = VT + ((size_t)b * CNKV + kvh) * CHD * CS;
  const int* mp = mask + b * CS;

  bf16x8 qf[2][2];
#pragma unroll
  for (int s = 0; s < 2; ++s) {
    qf[s][0] = *(const bf16x8*)(Qp + (s * 16 + rsel) * CHD + k8);
    qf[s][1] = *(const bf16x8*)(Qp + (s * 16 + rsel) * CHD + 32 + k8);
  }

  f32x4 o[2][4]; // o[s][nt][j] = O^T[nt*16+rowb+j][q0+s*16+rsel]
#pragma unroll
  for (int s = 0; s < 2; ++s)
#pragma unroll
    for (int nt = 0; nt < 4; ++nt) o[s][nt] = (f32x4){0.f, 0.f, 0.f, 0.f};
  float mrun[2] = {-3e38f, -3e38f}, lrun[2] = {0.f, 0.f};

  const int nkb = (qw >> 1) + 1;   // keys 0..nkb*64-1 cover rows q0..q0+31

  auto stageK = [&](int buf, int key0) {
#pragma unroll
    for (int i = 0; i < 4; ++i) {
      const int c = i * 128 + tid;         // 16B chunk 0..511
      const int r = c >> 3;                // key row 0..63
      const int swz = ((c & 7) ^ (r & 7)) * 8;
      gload_lds16(Kp + (size_t)(key0 + r) * CHD + swz, &Ks[buf][c * 8]);
    }
  };
  auto stageV = [&](int key0) {
#pragma unroll
    for (int i = 0; i < 4; ++i) {
      const int c = i * 128 + tid;
      const int r = c >> 3;                // d row 0..63
      const int swz = ((c & 7) ^ (r & 7)) * 8;
      gload_lds16(Vp + (size_t)r * CS + key0 + swz, &Vs[c * 8]);
    }
  };

  int mcur = mp[lane], mnext = 0;
  stageK(0, 0);
  __syncthreads();                          // K(0) landed

  for (int t = 0; t < nkb; ++t) {
    const int cur = t & 1;
    const int key0 = t * 64;
    const bool last = (t == nkb - 1);
    stageV(key0);                           // V(t) -> single buffer
    if (!last) {
      stageK(cur ^ 1, key0 + 64);           // K(t+1) prefetch
      mnext = mp[key0 + 64 + lane];
    }
    const unsigned long long kvbits = __ballot(mcur > 0);
    const int sz = rsel & 7;
    bf16x8 kc[8];
#pragma unroll
    for (int kt = 0; kt < 4; ++kt) {
      const int row = (kt * 16 + rsel) * 64;
      kc[kt * 2]     = *(const bf16x8*)&Ks[cur][row + ((hi ^ sz) << 3)];
      kc[kt * 2 + 1] = *(const bf16x8*)&Ks[cur][row + (((hi ^ 4) ^ sz) << 3)];
    }
    // S^T = K * Q^T for both sub-tiles (log2 domain via Q pre-scale)
    f32x4 st[2][4];
#pragma unroll
    for (int kt = 0; kt < 4; ++kt) {
#pragma unroll
      for (int s = 0; s < 2; ++s) {
        f32x4 a = (f32x4){0.f, 0.f, 0.f, 0.f};
        a = __builtin_amdgcn_mfma_f32_16x16x32_bf16(kc[kt * 2], qf[s][0], a, 0, 0, 0);
        a = __builtin_amdgcn_mfma_f32_16x16x32_bf16(kc[kt * 2 + 1], qf[s][1], a, 0, 0, 0);
        st[s][kt] = a;
      }
    }
    // masking per sub-tile (precise causal condition)
#pragma unroll
    for (int s = 0; s < 2; ++s) {
      const int qs = q0 + s * 16;
      const int qr = qs + rsel;
      if (kvbits != ~0ull || key0 + 63 > qs) {
#pragma unroll
        for (int kt = 0; kt < 4; ++kt)
#pragma unroll
          for (int j = 0; j < 4; ++j) {
            const int idx = kt * 16 + rowb + j;
            const bool bad = !((kvbits >> idx) & 1ull) || (key0 + idx > qr);
            if (bad) st[s][kt][j] = -1e9f;
          }
      }
    }
    // per-sub-tile softmax: lane-local 16-key max/sum, cross-hi via 2 shfl
#pragma unroll
    for (int s = 0; s < 2; ++s) {
      float pmax = st[s][0][0];
#pragma unroll
      for (int kt = 0; kt < 4; ++kt)
#pragma unroll
        for (int j = 0; j < 4; ++j) pmax = fmaxf(pmax, st[s][kt][j]);
      pmax = fmaxf(pmax, __shfl_xor(pmax, 16));
      pmax = fmaxf(pmax, __shfl_xor(pmax, 32));
      if (__any(pmax > mrun[s] + 8.0f)) {
        const float mn = fmaxf(mrun[s], pmax);
        const float al = exp2f(mrun[s] - mn);
        mrun[s] = mn;
        lrun[s] *= al;
#pragma unroll
        for (int nt = 0; nt < 4; ++nt)
#pragma unroll
          for (int j = 0; j < 4; ++j) o[s][nt][j] *= al;
      }
      float ps = 0.f;
#pragma unroll
      for (int kt = 0; kt < 4; ++kt)
#pragma unroll
        for (int j = 0; j < 4; ++j) {
          const float p = exp2f(st[s][kt][j] - mrun[s]);
          st[s][kt][j] = p;
          ps += p;
        }
      ps += __shfl_xor(ps, 16);
      ps += __shfl_xor(ps, 32);
      lrun[s] += ps;
    }
    // P^T -> LDS (padded stride, 8B packed writes)
#pragma unroll
    for (int s = 0; s < 2; ++s)
#pragma unroll
      for (int kt = 0; kt < 4; ++kt) {
        ushort4 pk;
        pk.x = bfbits(st[s][kt][0]);
        pk.y = bfbits(st[s][kt][1]);
        pk.z = bfbits(st[s][kt][2]);
        pk.w = bfbits(st[s][kt][3]);
        *(ushort4*)&P4[wave][s][rsel][kt * 16 + rowb] = pk;
      }
    __syncthreads();                        // MID: V(t) (+K(t+1)) DMAs drained
    bf16x8 vf[8];
#pragma unroll
    for (int nt = 0; nt < 4; ++nt) {
      const int row = (nt * 16 + rsel) * 64;
      vf[nt * 2]     = *(const bf16x8*)&Vs[row + ((hi ^ sz) << 3)];
      vf[nt * 2 + 1] = *(const bf16x8*)&Vs[row + (((hi ^ 4) ^ sz) << 3)];
    }
    bf16x8 pb[2][2];
#pragma unroll
    for (int s = 0; s < 2; ++s) {
      pb[s][0] = *(const bf16x8*)&P4[wave][s][rsel][k8];
      pb[s][1] = *(const bf16x8*)&P4[wave][s][rsel][32 + k8];
    }
    // O^T += V^T * P^T for both sub-tiles (shared vf)
#pragma unroll
    for (int nt = 0; nt < 4; ++nt)
#pragma unroll
      for (int s = 0; s < 2; ++s) {
        o[s][nt] = __builtin_amdgcn_mfma_f32_16x16x32_bf16(vf[nt * 2], pb[s][0], o[s][nt], 0, 0, 0);
        o[s][nt] = __builtin_amdgcn_mfma_f32_16x16x32_bf16(vf[nt * 2 + 1], pb[s][1], o[s][nt], 0, 0, 0);
      }
    __syncthreads();                        // END: reads done; next iter may overwrite
    mcur = mnext;
  }

#pragma unroll
  for (int s = 0; s < 2; ++s) {
    const int qr = q0 + s * 16 + rsel;
    const float qm = (mp[qr] > 0) ? 1.0f : 0.0f;
    const float inv = qm / fmaxf(lrun[s], 1e-20f);
    __hip_bfloat16* Orow = O + (((size_t)b * CS + qr) * CNH + h) * CHD;
#pragma unroll
    for (int nt = 0; nt < 4; ++nt) {
      ushort4 ok;
      ok.x = bfbits(o[s][nt][0] * inv);
      ok.y = bfbits(o[s][nt][1] * inv);
      ok.z = bfbits(o[s][nt][2] * inv);
      ok.w = bfbits(o[s][nt][3] * inv);
      *(ushort4*)(Orow + nt * 16 + rowb) = ok;
    }
  }
}

extern "C" void kernel_launch(void* const* d_in, const int* in_sizes, int n_in,
                              void* d_out, int out_size, void* d_ws, size_t ws_size,
                              hipStream_t stream) {
  const float* x = (const float*)d_in[0];
  const int* mask = (const int*)d_in[1];
  const float* w_qkv = (const float*)d_in[2];
  const float* w_o = (const float*)d_in[3];
  float* out = (float*)d_out;

  char* ws = (char*)d_ws;
  size_t off = 0;
  auto alloc = [&](size_t bytes) {
    char* p = ws + off;
    off += (bytes + 255) & ~(size_t)255;
    return p;
  };
  const size_t M = (size_t)CB * CS; // 4096
  __hip_bfloat16* x_bf  = (__hip_bfloat16*)alloc(M * CH * 2);
  __hip_bfloat16* wqkvT = (__hip_bfloat16*)alloc((size_t)CTHD * CH * 2);
  __hip_bfloat16* woT   = (__hip_bfloat16*)alloc((size_t)CH * CH * 2);
  __hip_bfloat16* qkv   = (__hip_bfloat16*)alloc(M * CTHD * 2);
  __hip_bfloat16* Qb    = (__hip_bfloat16*)alloc((size_t)CB * CNH * CS * CHD * 2);
  __hip_bfloat16* Kb    = (__hip_bfloat16*)alloc((size_t)CB * CNKV * CS * CHD * 2);
  __hip_bfloat16* VTb   = (__hip_bfloat16*)alloc((size_t)CB * CNKV * CHD * CS * 2);
  __hip_bfloat16* attnb = (__hip_bfloat16*)alloc(M * CH * 2);

  conv_bf16<<<(int)(M * CH / 4 / 256), 256, 0, stream>>>(x, x_bf, (int)(M * CH));
  transpose_conv<<<(CTHD / 32) * (CH / 32), 256, 0, stream>>>(w_qkv, wqkvT, CH, CTHD);
  transpose_conv<<<(CH / 32) * (CH / 32), 256, 0, stream>>>(w_o, woT, CH, CH);
  gemm_ph<__hip_bfloat16><<<(int)(M / 128) * (CTHD / 256), 512, 0, stream>>>(
      x_bf, wqkvT, qkv, (int)M, CTHD, CH);
  rope_extract<<<(int)(M * 40 * 32 / 256), 256, 0, stream>>>(qkv, Qb, Kb);
  v_transpose<<<CB * CNKV * 32, 256, 0, stream>>>(qkv, VTb);
  attn_fa<<<CB * CNKV * 128, 128, 0, stream>>>(Qb, Kb, VTb, mask, attnb);
  gemm_ph<float><<<(int)(M / 128) * (CH / 256), 512, 0, stream>>>(
      attnb, woT, out, (int)M, CH, CH);
}

// Round 15
// 231.344 us; speedup vs baseline: 1.2378x; 1.2378x over previous
//
#include <hip/hip_runtime.h>
#include <hip/hip_bf16.h>
#include <cstdint>
#include <cstddef>

typedef __attribute__((ext_vector_type(8))) short bf16x8;
typedef __attribute__((ext_vector_type(4))) float f32x4;

static constexpr int CB  = 2;
static constexpr int CS  = 2048;
static constexpr int CH  = 2048;
static constexpr int CNH = 32;
static constexpr int CNKV = 8;
static constexpr int CHD = 64;
static constexpr int CTHD = 3072; // (NH + 2*NKV)*HD

__device__ __forceinline__ void gload_lds16(const void* g, void* l) {
  __builtin_amdgcn_global_load_lds(
      (const __attribute__((address_space(1))) unsigned int*)g,
      (__attribute__((address_space(3))) unsigned int*)l, 16, 0, 0);
}

__device__ __forceinline__ unsigned short bfbits(float f) {
  __hip_bfloat16 h = __float2bfloat16(f);
  return *(unsigned short*)&h;
}

__device__ __forceinline__ float b2f(unsigned short s) {
  const unsigned u = (unsigned)s << 16;
  return __uint_as_float(u);
}

// ---------------- elementwise fp32 -> bf16 ----------------
__global__ void conv_bf16(const float* __restrict__ in, __hip_bfloat16* __restrict__ out, int n) {
  const int i = (blockIdx.x * 256 + threadIdx.x) * 4;
  if (i >= n) return;
  const float4 v = *(const float4*)(in + i);
  out[i]     = __float2bfloat16(v.x);
  out[i + 1] = __float2bfloat16(v.y);
  out[i + 2] = __float2bfloat16(v.z);
  out[i + 3] = __float2bfloat16(v.w);
}

// ---------------- RoPE trig table: tab[s][i] = (cos, sin) of s * 10000^(-i/32) ----------------
__global__ void trig_table(float2* __restrict__ tab) {
  const int idx = blockIdx.x * 256 + threadIdx.x;   // 2048*32 entries
  const int s = idx >> 5, i = idx & 31;
  const float inv = exp2f(-(float)i * (13.287712379549449f / 32.0f));
  const float ang = (float)s * inv;
  tab[idx] = make_float2(cosf(ang), sinf(ang));
}

// ---------------- tiled transpose + convert (fp32 RxC -> bf16 CxR) ----------------
__global__ __launch_bounds__(256) void transpose_conv(const float* __restrict__ in,
                                                      __hip_bfloat16* __restrict__ out,
                                                      int R, int Cc) {
  __shared__ float t[32][33];
  const int nbx = Cc >> 5;
  const int bx = blockIdx.x % nbx, by = blockIdx.x / nbx;
  const int c0 = bx << 5, r0 = by << 5;
  const int tx = threadIdx.x & 31, ty = threadIdx.x >> 5; // ty 0..7
#pragma unroll
  for (int j = 0; j < 32; j += 8)
    t[ty + j][tx] = in[(size_t)(r0 + ty + j) * Cc + c0 + tx];
  __syncthreads();
#pragma unroll
  for (int j = 0; j < 32; j += 8)
    out[(size_t)(c0 + ty + j) * R + r0 + tx] = __float2bfloat16(t[tx][ty + j]);
}

// ---------------- phased GEMM: 128x256 tile, BK=64, counted vmcnt (T3/T4/T5) ----------------
template <typename OutT>
__global__ __launch_bounds__(512) void gemm_ph(const __hip_bfloat16* __restrict__ A,
                                               const __hip_bfloat16* __restrict__ Bt,
                                               OutT* __restrict__ C, int M, int N, int K) {
  __shared__ __hip_bfloat16 As[2][128 * 64];
  __shared__ __hip_bfloat16 Bs[2][256 * 64];
  const int tid = threadIdx.x;
  const int lane = tid & 63;
  const int wave = tid >> 6;             // 0..7
  const int nTn = N >> 8;
  const int nwg = gridDim.x;
  const int wg = (blockIdx.x & 7) * (nwg >> 3) + (blockIdx.x >> 3);
  const int tm = wg / nTn, tn = wg % nTn;
  const size_t m0 = (size_t)tm * 128, n0 = (size_t)tn * 256;
  const __hip_bfloat16* Ag = A + m0 * K;
  const __hip_bfloat16* Bg = Bt + n0 * K;
  const int wr = wave >> 2, wc = wave & 3;
  const int rsel = lane & 15, hi = lane >> 4;

  f32x4 acc[4][4];
#pragma unroll
  for (int mf = 0; mf < 4; ++mf)
#pragma unroll
    for (int nf = 0; nf < 4; ++nf) acc[mf][nf] = (f32x4){0.f, 0.f, 0.f, 0.f};

  auto stageA = [&](int u) {
    const int k0 = u << 6, buf = u & 1;
#pragma unroll
    for (int i = 0; i < 2; ++i) {
      const int c = i * 512 + tid;       // chunk 0..1023
      const int r = c >> 3;
      const int swz = ((c & 7) ^ (r & 7)) << 3;
      gload_lds16(Ag + (size_t)r * K + k0 + swz, &As[buf][(i * 512 + wave * 64) * 8]);
    }
  };
  auto stageB = [&](int u) {
    const int k0 = u << 6, buf = u & 1;
#pragma unroll
    for (int i = 0; i < 4; ++i) {
      const int c = i * 512 + tid;       // chunk 0..2047
      const int r = c >> 3;
      const int swz = ((c & 7) ^ (r & 7)) << 3;
      gload_lds16(Bg + (size_t)r * K + k0 + swz, &Bs[buf][(i * 512 + wave * 64) * 8]);
    }
  };

  bf16x8 af[4][2];
  auto readA = [&](int buf) {
#pragma unroll
    for (int mf = 0; mf < 4; ++mf) {
      const int row = wr * 64 + mf * 16 + rsel;
      const int r7 = row & 7;
      af[mf][0] = *(const bf16x8*)&As[buf][row * 64 + ((hi ^ r7) << 3)];
      af[mf][1] = *(const bf16x8*)&As[buf][row * 64 + (((4 | hi) ^ r7) << 3)];
    }
  };
  auto mm = [&](int buf, int nfb) {
    bf16x8 bfr[2][2];
#pragma unroll
    for (int nf = 0; nf < 2; ++nf) {
      const int row = wc * 64 + (nfb + nf) * 16 + rsel;
      const int r7 = row & 7;
      bfr[nf][0] = *(const bf16x8*)&Bs[buf][row * 64 + ((hi ^ r7) << 3)];
      bfr[nf][1] = *(const bf16x8*)&Bs[buf][row * 64 + (((4 | hi) ^ r7) << 3)];
    }
    __builtin_amdgcn_s_setprio(1);
#pragma unroll
    for (int mf = 0; mf < 4; ++mf)
#pragma unroll
      for (int nf = 0; nf < 2; ++nf)
#pragma unroll
        for (int kk = 0; kk < 2; ++kk)
          acc[mf][nfb + nf] =
              __builtin_amdgcn_mfma_f32_16x16x32_bf16(af[mf][kk], bfr[nf][kk], acc[mf][nfb + nf], 0, 0, 0);
    __builtin_amdgcn_s_setprio(0);
  };

  const int T = K >> 7;                  // iterations (2 K-tiles each); K=2048 -> 8
  const int UMAX = 2 * T;
  stageA(0); stageB(0); stageA(1); stageB(1);

  for (int t = 0; t < T; ++t) {
    const int u0 = 2 * t, u1 = 2 * t + 1;
    // ---- phase 1 ----
    asm volatile("s_waitcnt vmcnt(2)" ::: "memory");
    __builtin_amdgcn_sched_barrier(0);
    __builtin_amdgcn_s_barrier();
    __builtin_amdgcn_sched_barrier(0);
    if (t >= 1) stageB(u1);
    readA(0);
    mm(0, 0);
    // ---- phase 2 ----
    __builtin_amdgcn_sched_barrier(0);
    __builtin_amdgcn_s_barrier();
    __builtin_amdgcn_sched_barrier(0);
    if (u0 + 2 < UMAX) stageA(u0 + 2);
    mm(0, 2);
    // ---- phase 3 ----
    if (t == T - 1) {
      asm volatile("s_waitcnt vmcnt(0)" ::: "memory");
    } else {
      asm volatile("s_waitcnt vmcnt(2)" ::: "memory");
    }
    __builtin_amdgcn_sched_barrier(0);
    __builtin_amdgcn_s_barrier();
    __builtin_amdgcn_sched_barrier(0);
    if (u0 + 2 < UMAX) stageB(u0 + 2);
    readA(1);
    mm(1, 0);
    // ---- phase 4 ----
    __builtin_amdgcn_sched_barrier(0);
    __builtin_amdgcn_s_barrier();
    __builtin_amdgcn_sched_barrier(0);
    if (u1 + 2 < UMAX) stageA(u1 + 2);
    mm(1, 2);
  }

  const int rowb = hi << 2;
#pragma unroll
  for (int mf = 0; mf < 4; ++mf)
#pragma unroll
    for (int nf = 0; nf < 4; ++nf) {
      const size_t r0 = m0 + wr * 64 + mf * 16 + rowb;
      const size_t cc = n0 + wc * 64 + nf * 16 + rsel;
#pragma unroll
      for (int j = 0; j < 4; ++j) {
        const float v = acc[mf][nf][j];
        if constexpr (sizeof(OutT) == 4)
          C[(r0 + j) * N + cc] = v;
        else
          C[(r0 + j) * N + cc] = __float2bfloat16(v);
      }
    }
}

// ---------------- RoPE + extract Q/K, table-based, 16B vectorized ----------------
// Thread handles 4 RoPE pairs (8 contiguous elements) of one (row, head):
// one bf16x8 load, 4 float2 table reads (32B contiguous), one bf16x8 store.
// Q heads pre-scaled by 0.125*log2e (softmax scale folded in).
__global__ void rope_extract(const __hip_bfloat16* __restrict__ qkv,
                             const float2* __restrict__ tab,
                             __hip_bfloat16* __restrict__ Q,
                             __hip_bfloat16* __restrict__ Kr) {
  const int idx = blockIdx.x * 256 + threadIdx.x;  // M*40*8 total
  const int t8 = idx & 7;            // 8-element chunk within the head
  const int hs = (idx >> 3) % 40;    // 0..31 = Q heads, 32..39 = K heads
  const int r = idx / (40 * 8);      // b*S + s
  const int srow = r & (CS - 1);
  const int b = r >> 11;
  const int colbase = (hs < CNH) ? hs * CHD : CH + (hs - CNH) * CHD;
  const bf16x8 v = *(const bf16x8*)(qkv + (size_t)r * CTHD + colbase + t8 * 8);
  const float2* tp = tab + srow * 32 + t8 * 4;
  const float scl = (hs < CNH) ? 0.18033688011112042f : 1.0f;
  union { unsigned short u[8]; bf16x8 v8; } o;
#pragma unroll
  for (int p = 0; p < 4; ++p) {
    const float t1 = b2f((unsigned short)v[2 * p]);
    const float t2 = b2f((unsigned short)v[2 * p + 1]);
    const float2 cs_ = tp[p];
    o.u[2 * p]     = bfbits((t1 * cs_.x - t2 * cs_.y) * scl);
    o.u[2 * p + 1] = bfbits((t1 * cs_.y + t2 * cs_.x) * scl);
  }
  __hip_bfloat16* dst;
  if (hs < CNH)
    dst = Q + ((((size_t)b * CNH + hs) * CS + srow) * CHD + t8 * 8);
  else
    dst = Kr + ((((size_t)b * CNKV + (hs - CNH)) * CS + srow) * CHD + t8 * 8);
  *(bf16x8*)dst = o.v8;
}

// ---------------- V extract + transpose: VT[b][kvh][d][s] ----------------
__global__ __launch_bounds__(256) void v_transpose(const __hip_bfloat16* __restrict__ qkv,
                                                   __hip_bfloat16* __restrict__ VT) {
  __shared__ __hip_bfloat16 t[64][72];
  const int bi = blockIdx.x;
  const int stile = bi & 31;
  const int kvh = (bi >> 5) & 7;
  const int b = bi >> 8;
  const int tx = threadIdx.x & 63;
  const int ty = threadIdx.x >> 6; // 0..3
  const int s0 = stile * 64;
#pragma unroll
  for (int j = 0; j < 16; ++j) {
    const int sl = ty * 16 + j;
    t[sl][tx] = qkv[(size_t)(b * CS + s0 + sl) * CTHD + (CH + CNKV * CHD) + kvh * CHD + tx];
  }
  __syncthreads();
#pragma unroll
  for (int j = 0; j < 16; ++j) {
    const int dl = ty * 16 + j;
    VT[(((size_t)b * CNKV + kvh) * CHD + dl) * CS + s0 + tx] = t[tx][dl];
  }
}

// ---------------- GQA causal flash attention (R12/R13 twice-validated config) ----------------
__global__ __launch_bounds__(256) void attn_fa(const __hip_bfloat16* __restrict__ Q,
                                               const __hip_bfloat16* __restrict__ Kr,
                                               const __hip_bfloat16* __restrict__ VT,
                                               const int* __restrict__ mask,
                                               __hip_bfloat16* __restrict__ O) {
  __shared__ __hip_bfloat16 Ks[2][64 * 64];
  __shared__ __hip_bfloat16 Vs[64 * 64];
  __shared__ __hip_bfloat16 P4[4][16][72];
  const int kvh = blockIdx.x & 7;          // xcd owns one kv-head
  const int slot = blockIdx.x >> 3;        // 0..255
  const int qw = 127 - (slot >> 1);        // heavy-first
  const int b = slot & 1;
  const int tid = threadIdx.x;
  const int wave = tid >> 6, lane = tid & 63;
  const int h = kvh * 4 + wave;            // this wave's q-head
  const int q0 = qw * 16;
  const int rsel = lane & 15;              // this lane's q-row
  const int hi = lane >> 4;                // 0..3
  const int k8 = hi * 8;
  const int rowb = hi * 4;
  const int qr = q0 + rsel;
  const __hip_bfloat16* Qp = Q + (((size_t)b * CNH + h) * CS + q0) * CHD;
  const __hip_bfloat16* Kp = Kr + ((size_t)b * CNKV + kvh) * CS * CHD;
  const __hip_bfloat16* Vp = VT + ((size_t)b * CNKV + kvh) * CHD * CS;
  const int* mp = mask + b * CS;
  __hip_bfloat16(*P)[72] = P4[wave];

  bf16x8 qf[2];
  qf[0] = *(const bf16x8*)(Qp + rsel * CHD + k8);
  qf[1] = *(const bf16x8*)(Qp + rsel * CHD + 32 + k8);

  f32x4 o[4]; // o[nt][j] = O^T[nt*16+rowb+j][qr]
#pragma unroll
  for (int nt = 0; nt < 4; ++nt) o[nt] = (f32x4){0.f, 0.f, 0.f, 0.f};
  float mrun = -3e38f, lrun = 0.f;

  const int nkb = (qw >> 2) + 1;

  auto stageK = [&](int buf, int key0) {
#pragma unroll
    for (int half = 0; half < 2; ++half) {
      const int c = half * 256 + tid;      // 16B chunk index 0..511
      const int r = c >> 3;                // row 0..63
      const int swz = ((c & 7) ^ (r & 7)) * 8;
      gload_lds16(Kp + (size_t)(key0 + r) * CHD + swz,
                  &Ks[buf][(half * 256 + wave * 64) * 8]);
    }
  };
  auto stageV = [&](int key0) {
#pragma unroll
    for (int half = 0; half < 2; ++half) {
      const int c = half * 256 + tid;
      const int r = c >> 3;
      const int swz = ((c & 7) ^ (r & 7)) * 8;
      gload_lds16(Vp + (size_t)r * CS + key0 + swz,
                  &Vs[(half * 256 + wave * 64) * 8]);
    }
  };

  int mcur = mp[lane], mnext = 0;
  stageK(0, 0);
  __syncthreads();                          // K(0) landed

  for (int t = 0; t < nkb; ++t) {
    const int cur = t & 1;
    const int key0 = t * 64;
    const bool last = (t == nkb - 1);
    stageV(key0);                           // V(t) -> single buffer (prev readers done)
    if (!last) {
      stageK(cur ^ 1, key0 + 64);           // K(t+1) prefetch
      mnext = mp[key0 + 64 + lane];
    }
    const unsigned long long kvbits = __ballot(mcur > 0);
    const int sz = rsel & 7;
    bf16x8 kc[8];
#pragma unroll
    for (int kt = 0; kt < 4; ++kt) {
      const int row = (kt * 16 + rsel) * 64;
      kc[kt * 2]     = *(const bf16x8*)&Ks[cur][row + ((hi ^ sz) << 3)];
      kc[kt * 2 + 1] = *(const bf16x8*)&Ks[cur][row + (((hi ^ 4) ^ sz) << 3)];
    }
    // S^T = K * Q^T (already in log2 domain via Q pre-scale)
    f32x4 st[4];
#pragma unroll
    for (int kt = 0; kt < 4; ++kt) {
      f32x4 s = (f32x4){0.f, 0.f, 0.f, 0.f};
      s = __builtin_amdgcn_mfma_f32_16x16x32_bf16(kc[kt * 2], qf[0], s, 0, 0, 0);
      s = __builtin_amdgcn_mfma_f32_16x16x32_bf16(kc[kt * 2 + 1], qf[1], s, 0, 0, 0);
      st[kt] = s;
    }
    if (!(kvbits == ~0ull && !last)) {
#pragma unroll
      for (int kt = 0; kt < 4; ++kt)
#pragma unroll
        for (int j = 0; j < 4; ++j) {
          const int idx = kt * 16 + rowb + j;
          const bool bad = !((kvbits >> idx) & 1ull) || (last && key0 + idx > qr);
          if (bad) st[kt][j] = -1e9f;
        }
    }
    // lane-local max over 16 keys, cross-hi combine via 2 shfl
    float pmax = st[0][0];
#pragma unroll
    for (int kt = 0; kt < 4; ++kt)
#pragma unroll
      for (int j = 0; j < 4; ++j) pmax = fmaxf(pmax, st[kt][j]);
    pmax = fmaxf(pmax, __shfl_xor(pmax, 16));
    pmax = fmaxf(pmax, __shfl_xor(pmax, 32));
    // defer-max: only rescale when the running max grew materially
    if (__any(pmax > mrun + 8.0f)) {
      const float mn = fmaxf(mrun, pmax);
      const float al = exp2f(mrun - mn);
      mrun = mn;
      lrun *= al;
#pragma unroll
      for (int nt = 0; nt < 4; ++nt)
#pragma unroll
        for (int j = 0; j < 4; ++j) o[nt][j] *= al;
    }
    float ps = 0.f;
#pragma unroll
    for (int kt = 0; kt < 4; ++kt)
#pragma unroll
      for (int j = 0; j < 4; ++j) {
        const float p = exp2f(st[kt][j] - mrun);
        st[kt][j] = p;
        ps += p;
      }
    ps += __shfl_xor(ps, 16);
    ps += __shfl_xor(ps, 32);
    lrun += ps;
    // P^T -> LDS as P[q][key] (8B packed writes, padded stride)
#pragma unroll
    for (int kt = 0; kt < 4; ++kt) {
      ushort4 pk;
      pk.x = bfbits(st[kt][0]);
      pk.y = bfbits(st[kt][1]);
      pk.z = bfbits(st[kt][2]);
      pk.w = bfbits(st[kt][3]);
      *(ushort4*)&P[rsel][kt * 16 + rowb] = pk;
    }
    __syncthreads();                        // MID: V(t) (+K(t+1)) DMAs drained
    const bf16x8 pb0 = *(const bf16x8*)&P[rsel][k8];
    const bf16x8 pb1 = *(const bf16x8*)&P[rsel][32 + k8];
    bf16x8 vf[8];
#pragma unroll
    for (int nt = 0; nt < 4; ++nt) {
      const int row = (nt * 16 + rsel) * 64;
      vf[nt * 2]     = *(const bf16x8*)&Vs[row + ((hi ^ sz) << 3)];
      vf[nt * 2 + 1] = *(const bf16x8*)&Vs[row + (((hi ^ 4) ^ sz) << 3)];
    }
    // O^T += V^T * P^T
#pragma unroll
    for (int nt = 0; nt < 4; ++nt) {
      o[nt] = __builtin_amdgcn_mfma_f32_16x16x32_bf16(vf[nt * 2], pb0, o[nt], 0, 0, 0);
      o[nt] = __builtin_amdgcn_mfma_f32_16x16x32_bf16(vf[nt * 2 + 1], pb1, o[nt], 0, 0, 0);
    }
    __syncthreads();                        // END: reads done; next iter may overwrite
    mcur = mnext;
  }

  const float qm = (mp[qr] > 0) ? 1.0f : 0.0f;
  const float inv = qm / fmaxf(lrun, 1e-20f);
  __hip_bfloat16* Orow = O + (((size_t)b * CS + qr) * CNH + h) * CHD;
#pragma unroll
  for (int nt = 0; nt < 4; ++nt) {
    ushort4 ok;
    ok.x = bfbits(o[nt][0] * inv);
    ok.y = bfbits(o[nt][1] * inv);
    ok.z = bfbits(o[nt][2] * inv);
    ok.w = bfbits(o[nt][3] * inv);
    *(ushort4*)(Orow + nt * 16 + rowb) = ok;
  }
}

extern "C" void kernel_launch(void* const* d_in, const int* in_sizes, int n_in,
                              void* d_out, int out_size, void* d_ws, size_t ws_size,
                              hipStream_t stream) {
  const float* x = (const float*)d_in[0];
  const int* mask = (const int*)d_in[1];
  const float* w_qkv = (const float*)d_in[2];
  const float* w_o = (const float*)d_in[3];
  float* out = (float*)d_out;

  char* ws = (char*)d_ws;
  size_t off = 0;
  auto alloc = [&](size_t bytes) {
    char* p = ws + off;
    off += (bytes + 255) & ~(size_t)255;
    return p;
  };
  const size_t M = (size_t)CB * CS; // 4096
  __hip_bfloat16* x_bf  = (__hip_bfloat16*)alloc(M * CH * 2);
  __hip_bfloat16* wqkvT = (__hip_bfloat16*)alloc((size_t)CTHD * CH * 2);
  __hip_bfloat16* woT   = (__hip_bfloat16*)alloc((size_t)CH * CH * 2);
  float2*         tab   = (float2*)alloc((size_t)CS * 32 * sizeof(float2));
  __hip_bfloat16* qkv   = (__hip_bfloat16*)alloc(M * CTHD * 2);
  __hip_bfloat16* Qb    = (__hip_bfloat16*)alloc((size_t)CB * CNH * CS * CHD * 2);
  __hip_bfloat16* Kb    = (__hip_bfloat16*)alloc((size_t)CB * CNKV * CS * CHD * 2);
  __hip_bfloat16* VTb   = (__hip_bfloat16*)alloc((size_t)CB * CNKV * CHD * CS * 2);
  __hip_bfloat16* attnb = (__hip_bfloat16*)alloc(M * CH * 2);

  conv_bf16<<<(int)(M * CH / 4 / 256), 256, 0, stream>>>(x, x_bf, (int)(M * CH));
  transpose_conv<<<(CTHD / 32) * (CH / 32), 256, 0, stream>>>(w_qkv, wqkvT, CH, CTHD);
  transpose_conv<<<(CH / 32) * (CH / 32), 256, 0, stream>>>(w_o, woT, CH, CH);
  trig_table<<<(CS * 32) / 256, 256, 0, stream>>>(tab);
  gemm_ph<__hip_bfloat16><<<(int)(M / 128) * (CTHD / 256), 512, 0, stream>>>(
      x_bf, wqkvT, qkv, (int)M, CTHD, CH);
  rope_extract<<<(int)(M * 40 * 8 / 256), 256, 0, stream>>>(qkv, tab, Qb, Kb);
  v_transpose<<<CB * CNKV * 32, 256, 0, stream>>>(qkv, VTb);
  attn_fa<<<CB * CNKV * 128, 256, 0, stream>>>(Qb, Kb, VTb, mask, attnb);
  gemm_ph<float><<<(int)(M / 128) * (CH / 256), 512, 0, stream>>>(
      attnb, woT, out, (int)M, CH, CH);
}

// Round 16
// 223.323 us; speedup vs baseline: 1.2823x; 1.0359x over previous
//
#include <hip/hip_runtime.h>
#include <hip/hip_bf16.h>
#include <cstdint>
#include <cstddef>

typedef __attribute__((ext_vector_type(8))) short bf16x8;
typedef __attribute__((ext_vector_type(4))) float f32x4;

static constexpr int CB  = 2;
static constexpr int CS  = 2048;
static constexpr int CH  = 2048;
static constexpr int CNH = 32;
static constexpr int CNKV = 8;
static constexpr int CHD = 64;
static constexpr int CTHD = 3072; // (NH + 2*NKV)*HD

__device__ __forceinline__ void gload_lds16(const void* g, void* l) {
  __builtin_amdgcn_global_load_lds(
      (const __attribute__((address_space(1))) unsigned int*)g,
      (__attribute__((address_space(3))) unsigned int*)l, 16, 0, 0);
}

__device__ __forceinline__ unsigned short bfbits(float f) {
  __hip_bfloat16 h = __float2bfloat16(f);
  return *(unsigned short*)&h;
}

__device__ __forceinline__ float b2f(unsigned short s) {
  const unsigned u = (unsigned)s << 16;
  return __uint_as_float(u);
}

// ---------------- fused pre-pass: conv_bf16 | w_qkv^T | w_o^T | trig table ----------------
// block ranges: [0,8192) conv, [8192,14336) wqkvT, [14336,18432) woT, [18432,18688) trig
__global__ __launch_bounds__(256) void prepass_fused(const float* __restrict__ x,
                                                     const float* __restrict__ w_qkv,
                                                     const float* __restrict__ w_o,
                                                     __hip_bfloat16* __restrict__ x_bf,
                                                     __hip_bfloat16* __restrict__ wqkvT,
                                                     __hip_bfloat16* __restrict__ woT,
                                                     float2* __restrict__ tab) {
  __shared__ float t[32][33];
  const int bid = blockIdx.x;
  if (bid < 8192) {                       // ---- x fp32 -> bf16 ----
    const int i = (bid * 256 + threadIdx.x) * 4;
    const float4 v = *(const float4*)(x + i);
    x_bf[i]     = __float2bfloat16(v.x);
    x_bf[i + 1] = __float2bfloat16(v.y);
    x_bf[i + 2] = __float2bfloat16(v.z);
    x_bf[i + 3] = __float2bfloat16(v.w);
    return;
  }
  if (bid >= 18432) {                     // ---- trig table ----
    const int idx = (bid - 18432) * 256 + threadIdx.x; // 2048*32 entries
    const int s = idx >> 5, i = idx & 31;
    const float inv = exp2f(-(float)i * (13.287712379549449f / 32.0f));
    const float ang = (float)s * inv;
    tab[idx] = make_float2(cosf(ang), sinf(ang));
    return;
  }
  // ---- tiled transpose + convert ----
  const float* in;
  __hip_bfloat16* out;
  int R, Cc, lb;
  if (bid < 14336) { in = w_qkv; out = wqkvT; R = CH; Cc = CTHD; lb = 8192; }
  else             { in = w_o;   out = woT;   R = CH; Cc = CH;   lb = 14336; }
  const int lbid = bid - lb;
  const int nbx = Cc >> 5;
  const int bx = lbid % nbx, by = lbid / nbx;
  const int c0 = bx << 5, r0 = by << 5;
  const int tx = threadIdx.x & 31, ty = threadIdx.x >> 5; // ty 0..7
#pragma unroll
  for (int j = 0; j < 32; j += 8)
    t[ty + j][tx] = in[(size_t)(r0 + ty + j) * Cc + c0 + tx];
  __syncthreads();
#pragma unroll
  for (int j = 0; j < 32; j += 8)
    out[(size_t)(c0 + ty + j) * R + r0 + tx] = __float2bfloat16(t[tx][ty + j]);
}

// ---------------- phased GEMM: 128x256 tile, BK=64, counted vmcnt (T3/T4/T5) ----------------
template <typename OutT>
__global__ __launch_bounds__(512) void gemm_ph(const __hip_bfloat16* __restrict__ A,
                                               const __hip_bfloat16* __restrict__ Bt,
                                               OutT* __restrict__ C, int M, int N, int K) {
  __shared__ __hip_bfloat16 As[2][128 * 64];
  __shared__ __hip_bfloat16 Bs[2][256 * 64];
  const int tid = threadIdx.x;
  const int lane = tid & 63;
  const int wave = tid >> 6;             // 0..7
  const int nTn = N >> 8;
  const int nwg = gridDim.x;
  const int wg = (blockIdx.x & 7) * (nwg >> 3) + (blockIdx.x >> 3);
  const int tm = wg / nTn, tn = wg % nTn;
  const size_t m0 = (size_t)tm * 128, n0 = (size_t)tn * 256;
  const __hip_bfloat16* Ag = A + m0 * K;
  const __hip_bfloat16* Bg = Bt + n0 * K;
  const int wr = wave >> 2, wc = wave & 3;
  const int rsel = lane & 15, hi = lane >> 4;

  f32x4 acc[4][4];
#pragma unroll
  for (int mf = 0; mf < 4; ++mf)
#pragma unroll
    for (int nf = 0; nf < 4; ++nf) acc[mf][nf] = (f32x4){0.f, 0.f, 0.f, 0.f};

  auto stageA = [&](int u) {
    const int k0 = u << 6, buf = u & 1;
#pragma unroll
    for (int i = 0; i < 2; ++i) {
      const int c = i * 512 + tid;       // chunk 0..1023
      const int r = c >> 3;
      const int swz = ((c & 7) ^ (r & 7)) << 3;
      gload_lds16(Ag + (size_t)r * K + k0 + swz, &As[buf][(i * 512 + wave * 64) * 8]);
    }
  };
  auto stageB = [&](int u) {
    const int k0 = u << 6, buf = u & 1;
#pragma unroll
    for (int i = 0; i < 4; ++i) {
      const int c = i * 512 + tid;       // chunk 0..2047
      const int r = c >> 3;
      const int swz = ((c & 7) ^ (r & 7)) << 3;
      gload_lds16(Bg + (size_t)r * K + k0 + swz, &Bs[buf][(i * 512 + wave * 64) * 8]);
    }
  };

  bf16x8 af[4][2];
  auto readA = [&](int buf) {
#pragma unroll
    for (int mf = 0; mf < 4; ++mf) {
      const int row = wr * 64 + mf * 16 + rsel;
      const int r7 = row & 7;
      af[mf][0] = *(const bf16x8*)&As[buf][row * 64 + ((hi ^ r7) << 3)];
      af[mf][1] = *(const bf16x8*)&As[buf][row * 64 + (((4 | hi) ^ r7) << 3)];
    }
  };
  auto mm = [&](int buf, int nfb) {
    bf16x8 bfr[2][2];
#pragma unroll
    for (int nf = 0; nf < 2; ++nf) {
      const int row = wc * 64 + (nfb + nf) * 16 + rsel;
      const int r7 = row & 7;
      bfr[nf][0] = *(const bf16x8*)&Bs[buf][row * 64 + ((hi ^ r7) << 3)];
      bfr[nf][1] = *(const bf16x8*)&Bs[buf][row * 64 + (((4 | hi) ^ r7) << 3)];
    }
    __builtin_amdgcn_s_setprio(1);
#pragma unroll
    for (int mf = 0; mf < 4; ++mf)
#pragma unroll
      for (int nf = 0; nf < 2; ++nf)
#pragma unroll
        for (int kk = 0; kk < 2; ++kk)
          acc[mf][nfb + nf] =
              __builtin_amdgcn_mfma_f32_16x16x32_bf16(af[mf][kk], bfr[nf][kk], acc[mf][nfb + nf], 0, 0, 0);
    __builtin_amdgcn_s_setprio(0);
  };

  const int T = K >> 7;                  // iterations (2 K-tiles each); K=2048 -> 8
  const int UMAX = 2 * T;
  stageA(0); stageB(0); stageA(1); stageB(1);

  for (int t = 0; t < T; ++t) {
    const int u0 = 2 * t, u1 = 2 * t + 1;
    // ---- phase 1 ----
    asm volatile("s_waitcnt vmcnt(2)" ::: "memory");
    __builtin_amdgcn_sched_barrier(0);
    __builtin_amdgcn_s_barrier();
    __builtin_amdgcn_sched_barrier(0);
    if (t >= 1) stageB(u1);
    readA(0);
    mm(0, 0);
    // ---- phase 2 ----
    __builtin_amdgcn_sched_barrier(0);
    __builtin_amdgcn_s_barrier();
    __builtin_amdgcn_sched_barrier(0);
    if (u0 + 2 < UMAX) stageA(u0 + 2);
    mm(0, 2);
    // ---- phase 3 ----
    if (t == T - 1) {
      asm volatile("s_waitcnt vmcnt(0)" ::: "memory");
    } else {
      asm volatile("s_waitcnt vmcnt(2)" ::: "memory");
    }
    __builtin_amdgcn_sched_barrier(0);
    __builtin_amdgcn_s_barrier();
    __builtin_amdgcn_sched_barrier(0);
    if (u0 + 2 < UMAX) stageB(u0 + 2);
    readA(1);
    mm(1, 0);
    // ---- phase 4 ----
    __builtin_amdgcn_sched_barrier(0);
    __builtin_amdgcn_s_barrier();
    __builtin_amdgcn_sched_barrier(0);
    if (u1 + 2 < UMAX) stageA(u1 + 2);
    mm(1, 2);
  }

  const int rowb = hi << 2;
#pragma unroll
  for (int mf = 0; mf < 4; ++mf)
#pragma unroll
    for (int nf = 0; nf < 4; ++nf) {
      const size_t r0 = m0 + wr * 64 + mf * 16 + rowb;
      const size_t cc = n0 + wc * 64 + nf * 16 + rsel;
#pragma unroll
      for (int j = 0; j < 4; ++j) {
        const float v = acc[mf][nf][j];
        if constexpr (sizeof(OutT) == 4)
          C[(r0 + j) * N + cc] = v;
        else
          C[(r0 + j) * N + cc] = __float2bfloat16(v);
      }
    }
}

// ---------------- fused post-pass: RoPE(Q,K) | V-transpose ----------------
// block ranges: [0,5120) rope (table-based, 16B vectorized), [5120,5632) v_transpose
__global__ __launch_bounds__(256) void ropevt_fused(const __hip_bfloat16* __restrict__ qkv,
                                                    const float2* __restrict__ tab,
                                                    __hip_bfloat16* __restrict__ Q,
                                                    __hip_bfloat16* __restrict__ Kr,
                                                    __hip_bfloat16* __restrict__ VT) {
  __shared__ __hip_bfloat16 t[64][72];
  const int bid = blockIdx.x;
  if (bid < 5120) {                       // ---- RoPE + extract Q/K ----
    const int idx = bid * 256 + threadIdx.x;  // M*40*8 total
    const int t8 = idx & 7;            // 8-element chunk within the head
    const int hs = (idx >> 3) % 40;    // 0..31 = Q heads, 32..39 = K heads
    const int r = idx / (40 * 8);      // b*S + s
    const int srow = r & (CS - 1);
    const int b = r >> 11;
    const int colbase = (hs < CNH) ? hs * CHD : CH + (hs - CNH) * CHD;
    const bf16x8 v = *(const bf16x8*)(qkv + (size_t)r * CTHD + colbase + t8 * 8);
    const float2* tp = tab + srow * 32 + t8 * 4;
    const float scl = (hs < CNH) ? 0.18033688011112042f : 1.0f;
    union { unsigned short u[8]; bf16x8 v8; } o;
#pragma unroll
    for (int p = 0; p < 4; ++p) {
      const float t1 = b2f((unsigned short)v[2 * p]);
      const float t2 = b2f((unsigned short)v[2 * p + 1]);
      const float2 cs_ = tp[p];
      o.u[2 * p]     = bfbits((t1 * cs_.x - t2 * cs_.y) * scl);
      o.u[2 * p + 1] = bfbits((t1 * cs_.y + t2 * cs_.x) * scl);
    }
    __hip_bfloat16* dst;
    if (hs < CNH)
      dst = Q + ((((size_t)b * CNH + hs) * CS + srow) * CHD + t8 * 8);
    else
      dst = Kr + ((((size_t)b * CNKV + (hs - CNH)) * CS + srow) * CHD + t8 * 8);
    *(bf16x8*)dst = o.v8;
    return;
  }
  // ---- V extract + transpose: VT[b][kvh][d][s] ----
  const int bi = bid - 5120;
  const int stile = bi & 31;
  const int kvh = (bi >> 5) & 7;
  const int b = bi >> 8;
  const int tx = threadIdx.x & 63;
  const int ty = threadIdx.x >> 6; // 0..3
  const int s0 = stile * 64;
#pragma unroll
  for (int j = 0; j < 16; ++j) {
    const int sl = ty * 16 + j;
    t[sl][tx] = qkv[(size_t)(b * CS + s0 + sl) * CTHD + (CH + CNKV * CHD) + kvh * CHD + tx];
  }
  __syncthreads();
#pragma unroll
  for (int j = 0; j < 16; ++j) {
    const int dl = ty * 16 + j;
    VT[(((size_t)b * CNKV + kvh) * CHD + dl) * CS + s0 + tx] = t[tx][dl];
  }
}

// ---------------- GQA causal flash attention (R8 exact, twice-validated) ----------------
__global__ __launch_bounds__(256) void attn_fa(const __hip_bfloat16* __restrict__ Q,
                                               const __hip_bfloat16* __restrict__ Kr,
                                               const __hip_bfloat16* __restrict__ VT,
                                               const int* __restrict__ mask,
                                               __hip_bfloat16* __restrict__ O) {
  __shared__ __hip_bfloat16 Ks[2][64 * 64];
  __shared__ __hip_bfloat16 Vs[2][64 * 64];
  __shared__ __hip_bfloat16 P4[4][16][72];
  const int kvh = blockIdx.x & 7;          // xcd owns one kv-head
  const int slot = blockIdx.x >> 3;        // 0..255
  const int qw = 127 - (slot >> 1);        // heavy-first
  const int b = slot & 1;
  const int tid = threadIdx.x;
  const int wave = tid >> 6, lane = tid & 63;
  const int h = kvh * 4 + wave;            // this wave's q-head
  const int q0 = qw * 16;
  const int rsel = lane & 15;              // this lane's q-row
  const int hi = lane >> 4;                // 0..3
  const int k8 = hi * 8;
  const int rowb = hi * 4;
  const int qr = q0 + rsel;
  const __hip_bfloat16* Qp = Q + (((size_t)b * CNH + h) * CS + q0) * CHD;
  const __hip_bfloat16* Kp = Kr + ((size_t)b * CNKV + kvh) * CS * CHD;
  const __hip_bfloat16* Vp = VT + ((size_t)b * CNKV + kvh) * CHD * CS;
  const int* mp = mask + b * CS;
  __hip_bfloat16(*P)[72] = P4[wave];

  bf16x8 qf[2];
  qf[0] = *(const bf16x8*)(Qp + rsel * CHD + k8);
  qf[1] = *(const bf16x8*)(Qp + rsel * CHD + 32 + k8);

  f32x4 o[4]; // o[nt][j] = O^T[nt*16+rowb+j][qr]
#pragma unroll
  for (int nt = 0; nt < 4; ++nt) o[nt] = (f32x4){0.f, 0.f, 0.f, 0.f};
  float mrun = -3e38f, lrun = 0.f;

  const int nkb = (qw >> 2) + 1;

  auto stage = [&](int buf, int key0) {
#pragma unroll
    for (int half = 0; half < 2; ++half) {
      const int c = half * 256 + tid;      // 16B chunk index 0..511
      const int r = c >> 3;                // row 0..63
      const int swz = ((c & 7) ^ (r & 7)) * 8;
      __hip_bfloat16* kd = &Ks[buf][(half * 256 + wave * 64) * 8];
      __hip_bfloat16* vd = &Vs[buf][(half * 256 + wave * 64) * 8];
      gload_lds16(Kp + (size_t)(key0 + r) * CHD + swz, kd);
      gload_lds16(Vp + (size_t)r * CS + key0 + swz, vd);
    }
  };

  int mcur = mp[lane], mnext = 0;
  stage(0, 0);
  __syncthreads();

  for (int t = 0; t < nkb; ++t) {
    const int cur = t & 1;
    const int key0 = t * 64;
    const bool last = (t == nkb - 1);
    if (!last) {
      stage(cur ^ 1, key0 + 64);
      mnext = mp[key0 + 64 + lane];
    }
    const unsigned long long kvbits = __ballot(mcur > 0);
    const int sz = rsel & 7;
    bf16x8 kc[8];
#pragma unroll
    for (int kt = 0; kt < 4; ++kt) {
      const int row = (kt * 16 + rsel) * 64;
      kc[kt * 2]     = *(const bf16x8*)&Ks[cur][row + ((hi ^ sz) << 3)];
      kc[kt * 2 + 1] = *(const bf16x8*)&Ks[cur][row + (((hi ^ 4) ^ sz) << 3)];
    }
    // S^T = K * Q^T (already in log2 domain via Q pre-scale)
    f32x4 st[4];
#pragma unroll
    for (int kt = 0; kt < 4; ++kt) {
      f32x4 s = (f32x4){0.f, 0.f, 0.f, 0.f};
      s = __builtin_amdgcn_mfma_f32_16x16x32_bf16(kc[kt * 2], qf[0], s, 0, 0, 0);
      s = __builtin_amdgcn_mfma_f32_16x16x32_bf16(kc[kt * 2 + 1], qf[1], s, 0, 0, 0);
      st[kt] = s;
    }
    // V fragments issued now; consumed after softmax
    bf16x8 vf[8];
#pragma unroll
    for (int nt = 0; nt < 4; ++nt) {
      const int row = (nt * 16 + rsel) * 64;
      vf[nt * 2]     = *(const bf16x8*)&Vs[cur][row + ((hi ^ sz) << 3)];
      vf[nt * 2 + 1] = *(const bf16x8*)&Vs[cur][row + (((hi ^ 4) ^ sz) << 3)];
    }
    if (!(kvbits == ~0ull && !last)) {
#pragma unroll
      for (int kt = 0; kt < 4; ++kt)
#pragma unroll
        for (int j = 0; j < 4; ++j) {
          const int idx = kt * 16 + rowb + j;
          const bool bad = !((kvbits >> idx) & 1ull) || (last && key0 + idx > qr);
          if (bad) st[kt][j] = -1e9f;
        }
    }
    // lane-local max over 16 keys, cross-hi combine via 2 shfl
    float pmax = st[0][0];
#pragma unroll
    for (int kt = 0; kt < 4; ++kt)
#pragma unroll
      for (int j = 0; j < 4; ++j) pmax = fmaxf(pmax, st[kt][j]);
    pmax = fmaxf(pmax, __shfl_xor(pmax, 16));
    pmax = fmaxf(pmax, __shfl_xor(pmax, 32));
    // defer-max: only rescale when the running max grew materially
    if (__any(pmax > mrun + 8.0f)) {
      const float mn = fmaxf(mrun, pmax);
      const float al = exp2f(mrun - mn);
      mrun = mn;
      lrun *= al;
#pragma unroll
      for (int nt = 0; nt < 4; ++nt)
#pragma unroll
        for (int j = 0; j < 4; ++j) o[nt][j] *= al;
    }
    float ps = 0.f;
#pragma unroll
    for (int kt = 0; kt < 4; ++kt)
#pragma unroll
      for (int j = 0; j < 4; ++j) {
        const float p = exp2f(st[kt][j] - mrun);
        st[kt][j] = p;
        ps += p;
      }
    ps += __shfl_xor(ps, 16);
    ps += __shfl_xor(ps, 32);
    lrun += ps;
    // P^T -> LDS as P[q][key] (8B packed writes, padded stride), read as B-fragments
#pragma unroll
    for (int kt = 0; kt < 4; ++kt) {
      ushort4 pk;
      pk.x = bfbits(st[kt][0]);
      pk.y = bfbits(st[kt][1]);
      pk.z = bfbits(st[kt][2]);
      pk.w = bfbits(st[kt][3]);
      *(ushort4*)&P[rsel][kt * 16 + rowb] = pk;
    }
    const bf16x8 pb0 = *(const bf16x8*)&P[rsel][k8];
    const bf16x8 pb1 = *(const bf16x8*)&P[rsel][32 + k8];
    // O^T += V^T * P^T
#pragma unroll
    for (int nt = 0; nt < 4; ++nt) {
      o[nt] = __builtin_amdgcn_mfma_f32_16x16x32_bf16(vf[nt * 2], pb0, o[nt], 0, 0, 0);
      o[nt] = __builtin_amdgcn_mfma_f32_16x16x32_bf16(vf[nt * 2 + 1], pb1, o[nt], 0, 0, 0);
    }
    __syncthreads();
    mcur = mnext;
  }

  const float qm = (mp[qr] > 0) ? 1.0f : 0.0f;
  const float inv = qm / fmaxf(lrun, 1e-20f);
  __hip_bfloat16* Orow = O + (((size_t)b * CS + qr) * CNH + h) * CHD;
#pragma unroll
  for (int nt = 0; nt < 4; ++nt) {
    ushort4 ok;
    ok.x = bfbits(o[nt][0] * inv);
    ok.y = bfbits(o[nt][1] * inv);
    ok.z = bfbits(o[nt][2] * inv);
    ok.w = bfbits(o[nt][3] * inv);
    *(ushort4*)(Orow + nt * 16 + rowb) = ok;
  }
}

extern "C" void kernel_launch(void* const* d_in, const int* in_sizes, int n_in,
                              void* d_out, int out_size, void* d_ws, size_t ws_size,
                              hipStream_t stream) {
  const float* x = (const float*)d_in[0];
  const int* mask = (const int*)d_in[1];
  const float* w_qkv = (const float*)d_in[2];
  const float* w_o = (const float*)d_in[3];
  float* out = (float*)d_out;

  char* ws = (char*)d_ws;
  size_t off = 0;
  auto alloc = [&](size_t bytes) {
    char* p = ws + off;
    off += (bytes + 255) & ~(size_t)255;
    return p;
  };
  const size_t M = (size_t)CB * CS; // 4096
  __hip_bfloat16* x_bf  = (__hip_bfloat16*)alloc(M * CH * 2);
  __hip_bfloat16* wqkvT = (__hip_bfloat16*)alloc((size_t)CTHD * CH * 2);
  __hip_bfloat16* woT   = (__hip_bfloat16*)alloc((size_t)CH * CH * 2);
  float2*         tab   = (float2*)alloc((size_t)CS * 32 * sizeof(float2));
  __hip_bfloat16* qkv   = (__hip_bfloat16*)alloc(M * CTHD * 2);
  __hip_bfloat16* Qb    = (__hip_bfloat16*)alloc((size_t)CB * CNH * CS * CHD * 2);
  __hip_bfloat16* Kb    = (__hip_bfloat16*)alloc((size_t)CB * CNKV * CS * CHD * 2);
  __hip_bfloat16* VTb   = (__hip_bfloat16*)alloc((size_t)CB * CNKV * CHD * CS * 2);
  __hip_bfloat16* attnb = (__hip_bfloat16*)alloc(M * CH * 2);

  prepass_fused<<<18688, 256, 0, stream>>>(x, w_qkv, w_o, x_bf, wqkvT, woT, tab);
  gemm_ph<__hip_bfloat16><<<(int)(M / 128) * (CTHD / 256), 512, 0, stream>>>(
      x_bf, wqkvT, qkv, (int)M, CTHD, CH);
  ropevt_fused<<<5632, 256, 0, stream>>>(qkv, tab, Qb, Kb, VTb);
  attn_fa<<<CB * CNKV * 128, 256, 0, stream>>>(Qb, Kb, VTb, mask, attnb);
  gemm_ph<float><<<(int)(M / 128) * (CH / 256), 512, 0, stream>>>(
      attnb, woT, out, (int)M, CH, CH);
}